// Round 1
// baseline (31.805 us; speedup 1.0000x reference)
//
#include <hip/hip_runtime.h>

#define NC 256   // channels
#define NK 16    // cluster centers

__global__ __launch_bounds__(256) void lutfq_kernel(
    const float4* __restrict__ x,
    const float*  __restrict__ scales,
    const float*  __restrict__ centers,
    float4*       __restrict__ out,
    int n4)
{
    // per-channel precomputed: denominator (s+eps) and output scale (s/128)
    __shared__ float s_den[NC];
    __shared__ float s_out[NC];

    // 16 rounded centers, wave-uniform -> registers
    float cen[NK];
#pragma unroll
    for (int k = 0; k < NK; ++k) cen[k] = rintf(centers[k]);  // round half-to-even == jnp.round

    const int tid = threadIdx.x;
    {
        // blockDim == 256 == NC: one scale per thread
        float s = scales[tid];
        s_den[tid] = s + 1e-8f;         // float32 add, same as ref
        s_out[tid] = s * 0.0078125f;    // s/128, exact
    }
    __syncthreads();

    const int stride = gridDim.x * blockDim.x;
    for (int i = blockIdx.x * blockDim.x + tid; i < n4; i += stride) {
        float4 xv = x[i];
        const int c4 = (i & (NC / 4 - 1)) * 4;  // first channel of this float4

        float4 dn = *reinterpret_cast<const float4*>(&s_den[c4]);
        float4 so = *reinterpret_cast<const float4*>(&s_out[c4]);

        float xin[4] = {xv.x, xv.y, xv.z, xv.w};
        float den[4] = {dn.x, dn.y, dn.z, dn.w};
        float sov[4] = {so.x, so.y, so.z, so.w};
        float rv[4];

#pragma unroll
        for (int j = 0; j < 4; ++j) {
            // t = clip(x/(s+eps)*128, -128, 127)  -- IEEE div, then exact *128
            float t = (xin[j] / den[j]) * 128.0f;
            t = fminf(fmaxf(t, -128.0f), 127.0f);

            // argmin over 16 centers, strict < keeps FIRST index on ties (jnp.argmin)
            float best = 3.4e38f;
            float bc = 0.0f;
#pragma unroll
            for (int k = 0; k < NK; ++k) {
                float d = fabsf(t - cen[k]);
                bool p = d < best;
                best = p ? d : best;
                bc   = p ? cen[k] : bc;
            }
            rv[j] = bc * sov[j];  // c*(s/128) == (c/128)*s bit-exactly
        }

        float4 r;
        r.x = rv[0]; r.y = rv[1]; r.z = rv[2]; r.w = rv[3];
        out[i] = r;
    }
}

extern "C" void kernel_launch(void* const* d_in, const int* in_sizes, int n_in,
                              void* d_out, int out_size, void* d_ws, size_t ws_size,
                              hipStream_t stream) {
    const float* x       = (const float*)d_in[0];
    const float* scales  = (const float*)d_in[1];
    const float* centers = (const float*)d_in[2];
    float* out = (float*)d_out;

    int n4 = out_size / 4;  // total elements divisible by 4 (C=256)
    int blocks = (n4 + 255) / 256;
    if (blocks > 2048) blocks = 2048;  // grid-stride; ~8 blocks/CU

    lutfq_kernel<<<blocks, 256, 0, stream>>>(
        (const float4*)x, scales, centers, (float4*)out, n4);
}

// Round 2
// 23.642 us; speedup vs baseline: 1.3453x; 1.3453x over previous
//
#include <hip/hip_runtime.h>

#define NC 256   // channels
#define NK 16    // cluster centers

// Exact replica of the reference's per-element argmin (float semantics):
// scan k ascending, strict <  -> first index wins ties.
__device__ __forceinline__ float argmin16(float t, const float* cen) {
    float best = 3.4e38f;
    float bc = 0.0f;
#pragma unroll
    for (int k = 0; k < NK; ++k) {
        float d = fabsf(t - cen[k]);
        bool p = d < best;
        best = p ? d : best;
        bc   = p ? cen[k] : bc;
    }
    return bc;
}

__global__ __launch_bounds__(256) void lutfq_kernel(
    const float4* __restrict__ x,
    const float*  __restrict__ scales,
    const float*  __restrict__ centers,
    float4*       __restrict__ out,
    int n4)
{
    __shared__ float  s_den[NC];   // s + 1e-8
    __shared__ float  s_out[NC];   // s / 128
    __shared__ float2 s_lut[512];  // .x = interior center for bucket, .y = exact-edge center

    // 16 rounded centers (wave-uniform -> scalar regs)
    float cen[NK];
#pragma unroll
    for (int k = 0; k < NK; ++k) cen[k] = rintf(centers[k]);  // round-half-to-even == jnp.round

    const int tid = threadIdx.x;
    {
        float s = scales[tid];          // blockDim == 256 == NC
        s_den[tid] = s + 1e-8f;
        s_out[tid] = s * 0.0078125f;    // exact
    }
    // Build the 512-bucket LUT. Bucket ub covers t in [fl/2, (fl+1)/2), fl = ub-256.
    // .y is the ref argmin at EXACTLY t = fl/2 (same float as any runtime t with frac==0).
    // .x is the argmin anywhere in the safe interior (constant there; rep = fl/2 + 0.25).
    for (int ub = tid; ub < 512; ub += 256) {
        float fl = (float)(ub - 256);
        float te = 0.5f * fl;           // exact
        float ti = te + 0.25f;          // exact
        float2 v;
        v.x = argmin16(ti, cen);
        v.y = argmin16(te, cen);
        s_lut[ub] = v;
    }
    __syncthreads();

    const int stride = gridDim.x * blockDim.x;
    for (int i = blockIdx.x * blockDim.x + tid; i < n4; i += stride) {
        float4 xv = x[i];
        const int c4 = (i & (NC / 4 - 1)) * 4;  // first channel of this float4

        float4 dn = *reinterpret_cast<const float4*>(&s_den[c4]);
        float4 so = *reinterpret_cast<const float4*>(&s_out[c4]);

        float xin[4] = {xv.x, xv.y, xv.z, xv.w};
        float den[4] = {dn.x, dn.y, dn.z, dn.w};
        float sov[4] = {so.x, so.y, so.z, so.w};
        float rv[4];

#pragma unroll
        for (int j = 0; j < 4; ++j) {
            // t = clip(x/(s+eps)*128, -128, 127) -- IEEE div, exact *128, same as ref
            float t = (xin[j] / den[j]) * 128.0f;
            t = fminf(fmaxf(t, -128.0f), 127.0f);

            float u2   = 2.0f * t;          // exact (pow2 mul, |u2|<=256)
            float fl   = floorf(u2);        // exact
            float frac = u2 - fl;           // ~exact; only used for band test
            int   ub   = (int)fl + 256;     // 0..510

            float2 lv = s_lut[ub];
            // frac==0  <=>  t == fl/2 exactly  -> edge LUT is a bit-exact ref replay
            float c = (frac == 0.0f) ? lv.y : lv.x;

            // Float-rounding band near a bucket edge (excl. the exact edge): the ref's
            // rounded |t-c_k| comparisons can tie -> replay the exact argmin. Rare
            // (~1e-3 of elements); exec-masked, skipped by s_cbranch_execz otherwise.
            bool band = (frac < 0x1p-12f || frac > 1.0f - 0x1p-12f) && (frac != 0.0f);
            if (band) {
                c = argmin16(t, cen);
            }

            rv[j] = c * sov[j];  // c*(s/128) == (c/128)*s bit-exactly
        }

        float4 r;
        r.x = rv[0]; r.y = rv[1]; r.z = rv[2]; r.w = rv[3];
        out[i] = r;
    }
}

extern "C" void kernel_launch(void* const* d_in, const int* in_sizes, int n_in,
                              void* d_out, int out_size, void* d_ws, size_t ws_size,
                              hipStream_t stream) {
    const float* x       = (const float*)d_in[0];
    const float* scales  = (const float*)d_in[1];
    const float* centers = (const float*)d_in[2];
    float* out = (float*)d_out;

    int n4 = out_size / 4;
    int blocks = (n4 + 255) / 256;
    if (blocks > 2048) blocks = 2048;  // grid-stride; amortizes LUT build ~6x

    lutfq_kernel<<<blocks, 256, 0, stream>>>(
        (const float4*)x, scales, centers, (float4*)out, n4);
}